// Round 7
// baseline (271.333 us; speedup 1.0000x reference)
//
#include <hip/hip_runtime.h>
#include <hip/hip_bf16.h>

// B=4, T=2048, E=768, H=12, hd=64.
// Round 7:
//   - attn: identical to round 6 EXCEPT __launch_bounds__(256) (no min-wave
//     bound). Round 6's (256,4) forced VGPR 64 -> remat/spill killed the
//     prefetch. Theory: VGPR floats to ~150, prefetch survives, big win.
//   - GEMMs: m97-style global_load_lds width=16, linear [128][32] LDS
//     (no reg staging). Accept 8-way ds_read conflicts (off critical path).

#define BB 4
#define TT 2048
#define EE 768
#define HH 12
#define HD 64
#define KK 768
#define BTE (BB*TT*EE)  // 6291456

typedef __attribute__((ext_vector_type(8))) short bf16x8;
typedef __attribute__((ext_vector_type(4))) float f32x4;
typedef __attribute__((ext_vector_type(4))) int i32x4;

#define QSC 0.18033688011112042f   // 0.125 * log2(e)

#define GLOAD16(gp, lp) \
    __builtin_amdgcn_global_load_lds( \
        (const __attribute__((address_space(1))) unsigned*)(gp), \
        (__attribute__((address_space(3))) unsigned*)(lp), 16, 0, 0)

static __device__ __forceinline__ unsigned short f2bf(float f) {
    unsigned u = __builtin_bit_cast(unsigned, f);
    u += 0x7fffu + ((u >> 16) & 1u);   // RNE
    return (unsigned short)(u >> 16);
}

static __device__ __forceinline__ unsigned cvt_pk_bf16(float lo, float hi) {
    unsigned r;
    asm("v_cvt_pk_bf16_f32 %0, %1, %2" : "=v"(r) : "v"(lo), "v"(hi));
    return r;
}

// ---------------------------------------------------------------------------
__global__ __launch_bounds__(256)
void convx_kernel(const float* __restrict__ x, unsigned short* __restrict__ xb) {
    const size_t i = ((size_t)blockIdx.x * 256 + threadIdx.x) * 8;
    float4 a = *(const float4*)&x[i];
    float4 b = *(const float4*)&x[i + 4];
    ushort4 lo, hi;
    lo.x = f2bf(a.x); lo.y = f2bf(a.y); lo.z = f2bf(a.z); lo.w = f2bf(a.w);
    hi.x = f2bf(b.x); hi.y = f2bf(b.y); hi.z = f2bf(b.z); hi.w = f2bf(b.w);
    *(ushort4*)&xb[i] = lo;
    *(ushort4*)&xb[i + 4] = hi;
}

// ---------------------------------------------------------------------------
__global__ __launch_bounds__(256)
void transw_kernel(const float* __restrict__ W, unsigned short* __restrict__ Wt, int N) {
    __shared__ unsigned short Ts[64][72];
    const int n0 = blockIdx.x * 64;
    const int k0 = blockIdx.y * 64;
    const int tid = threadIdx.x;
    {
        const int r = tid >> 4;
        const int c4 = (tid & 15) << 2;
#pragma unroll
        for (int i = 0; i < 4; ++i) {
            const int k = r + i * 16;
            float4 w4 = *(const float4*)&W[(size_t)(k0 + k) * N + n0 + c4];
            Ts[k][c4 + 0] = f2bf(w4.x); Ts[k][c4 + 1] = f2bf(w4.y);
            Ts[k][c4 + 2] = f2bf(w4.z); Ts[k][c4 + 3] = f2bf(w4.w);
        }
    }
    __syncthreads();
#pragma unroll
    for (int i = 0; i < 2; ++i) {
        const int idx = tid + i * 256;
        const int n = idx >> 3;
        const int ch = idx & 7;
        ushort4 p0, p1;
        p0.x = Ts[ch * 8 + 0][n]; p0.y = Ts[ch * 8 + 1][n];
        p0.z = Ts[ch * 8 + 2][n]; p0.w = Ts[ch * 8 + 3][n];
        p1.x = Ts[ch * 8 + 4][n]; p1.y = Ts[ch * 8 + 5][n];
        p1.z = Ts[ch * 8 + 6][n]; p1.w = Ts[ch * 8 + 7][n];
        *(ushort4*)&Wt[(size_t)(n0 + n) * KK + k0 + ch * 8] = p0;
        *(ushort4*)&Wt[(size_t)(n0 + n) * KK + k0 + ch * 8 + 4] = p1;
    }
}

// ---------------------------------------------------------------------------
// bf16 MFMA GEMM, m97-style: global_load_lds(16) into LINEAR [128][32] LDS.
// 128x128 tile, BK=32, 4 waves (2x2), 4x4 frags of 16x16x32.
// ---------------------------------------------------------------------------
template<int MODE>
__global__ __launch_bounds__(256)
void mfma_gemm_kernel(const unsigned short* __restrict__ A,
                      const unsigned short* __restrict__ Wt,
                      unsigned short* __restrict__ q_ws,
                      unsigned short* __restrict__ k_ws,
                      unsigned short* __restrict__ v_ws,
                      float* __restrict__ outf) {
    __shared__ __align__(16) unsigned short As[128 * 32];   // linear, 64B rows
    __shared__ __align__(16) unsigned short Bs[128 * 32];
    const int bx = blockIdx.x;
    const int by = blockIdx.y;
    const int tid = threadIdx.x;
    const int w = tid >> 6, lane = tid & 63;
    const int c = lane & 15, g = lane >> 4;
    const int wr = w >> 1, wc = w & 1;
    const int m0 = by * 128, n0 = bx * 128;

    const int lrow = lane >> 2;        // 0..15
    const int lch  = (lane & 3) * 8;   // shorts within 32-elem row

    const unsigned short* Ap = A  + (size_t)m0 * KK;
    const unsigned short* Bp = Wt + (size_t)n0 * KK;

    f32x4 acc[4][4] = {};

    for (int kt = 0; kt < KK / 32; ++kt) {
        const int k0 = kt * 32;
        __syncthreads();   // prev iter's frag reads complete
        // dest = wave-uniform base + lane*16B (HW); 16 rows per instruction
        GLOAD16(Ap + (size_t)(w * 32 +  0 + lrow) * KK + k0 + lch, &As[(w * 32 +  0) * 32]);
        GLOAD16(Ap + (size_t)(w * 32 + 16 + lrow) * KK + k0 + lch, &As[(w * 32 + 16) * 32]);
        GLOAD16(Bp + (size_t)(w * 32 +  0 + lrow) * KK + k0 + lch, &Bs[(w * 32 +  0) * 32]);
        GLOAD16(Bp + (size_t)(w * 32 + 16 + lrow) * KK + k0 + lch, &Bs[(w * 32 + 16) * 32]);
        __syncthreads();   // drains vmcnt -> LDS data visible

        bf16x8 af[4], bfr[4];
#pragma unroll
        for (int m = 0; m < 4; ++m)
            af[m] = *(const bf16x8*)&As[(wr * 64 + m * 16 + c) * 32 + g * 8];
#pragma unroll
        for (int n = 0; n < 4; ++n)
            bfr[n] = *(const bf16x8*)&Bs[(wc * 64 + n * 16 + c) * 32 + g * 8];
#pragma unroll
        for (int m = 0; m < 4; ++m)
#pragma unroll
            for (int n = 0; n < 4; ++n)
                acc[m][n] = __builtin_amdgcn_mfma_f32_16x16x32_bf16(af[m], bfr[n], acc[m][n], 0, 0, 0);
    }

    if (MODE == 0) {
        const int which = n0 / EE;
        const int h = (n0 % EE) / HD + wc;
        const int b = m0 / TT;
        const int tb = (m0 % TT) + wr * 64;
        if (which < 2) {
            const float sc_ = (which == 0) ? QSC : 1.0f;   // pre-scale q
            unsigned short* dst = (which == 0) ? q_ws : k_ws;
            unsigned short* base = dst + (((size_t)b * HH + h) * TT) * HD;
#pragma unroll
            for (int m = 0; m < 4; ++m)
#pragma unroll
                for (int n = 0; n < 4; ++n)
#pragma unroll
                    for (int j = 0; j < 4; ++j)
                        base[(size_t)(tb + m * 16 + 4 * g + j) * HD + n * 16 + c] =
                            f2bf(acc[m][n][j] * sc_);
        } else {
            unsigned short* base = v_ws + (((size_t)b * HH + h) * HD) * TT;
#pragma unroll
            for (int m = 0; m < 4; ++m)
#pragma unroll
                for (int n = 0; n < 4; ++n)
#pragma unroll
                    for (int j = 0; j < 4; ++j)
                        base[(size_t)(n * 16 + c) * TT + tb + m * 16 + 4 * g + j] =
                            f2bf(acc[m][n][j]);
        }
    } else {
#pragma unroll
        for (int m = 0; m < 4; ++m)
#pragma unroll
            for (int n = 0; n < 4; ++n)
#pragma unroll
                for (int j = 0; j < 4; ++j)
                    outf[(size_t)(m0 + wr * 64 + m * 16 + 4 * g + j) * EE
                         + n0 + wc * 64 + n * 16 + c] = acc[m][n][j];
    }
}

// ---------------------------------------------------------------------------
// Swapped-QK^T MFMA flash attention (round-6 structure).
// ONLY change: __launch_bounds__(256) — no min-wave bound, VGPRs float so
// the prefetch registers and softmax state stay live (no remat/spill).
// ---------------------------------------------------------------------------
__global__ __launch_bounds__(256)
void attn_kernel(const unsigned short* __restrict__ q,
                 const unsigned short* __restrict__ k,
                 const unsigned short* __restrict__ vt,
                 unsigned short* __restrict__ attn_b) {
    __shared__ __align__(16) unsigned short Ks[2][64 * 72];   // [key][d]
    __shared__ __align__(16) unsigned short Vt[2][64 * 72];   // [d][key]

    const int qi = (TT / 128 - 1) - blockIdx.x;   // heavy blocks first
    const int h = blockIdx.y, b = blockIdx.z;
    const int tid = threadIdx.x;
    const int w = tid >> 6;
    const int lane = tid & 63;
    const int c = lane & 15;
    const int g = lane >> 4;

    const size_t head_off = (size_t)(b * HH + h) * TT * HD;
    const unsigned short* qp = q + head_off;
    const unsigned short* kp = k + head_off;
    const unsigned short* vp = vt + head_off;   // [64][T]

    const int q0w = qi * 128 + w * 32;

    bf16x8 qa0[2], qa1[2];
#pragma unroll
    for (int f = 0; f < 2; ++f) {
        qa0[f] = *(const bf16x8*)&qp[(size_t)(q0w + f * 16 + c) * HD + g * 8];
        qa1[f] = *(const bf16x8*)&qp[(size_t)(q0w + f * 16 + c) * HD + 32 + g * 8];
    }

    f32x4 o[2][4] = {};
    float m_r[2] = {-INFINITY, -INFINITY};
    float l_r[2] = {0.f, 0.f};

    const int skey = tid >> 2;       // 0..63
    const int sc = tid & 3;

    const int ktiles = 2 * qi + 2;

    // prologue: tile 0 -> buf 0
    uint4 kA = *(const uint4*)&kp[(size_t)skey * HD + sc * 16];
    uint4 kB = *(const uint4*)&kp[(size_t)skey * HD + sc * 16 + 8];
    uint4 vA = *(const uint4*)&vp[(size_t)skey * TT + sc * 16];
    uint4 vB = *(const uint4*)&vp[(size_t)skey * TT + sc * 16 + 8];
    *(uint4*)&Ks[0][skey * 72 + sc * 16]     = kA;
    *(uint4*)&Ks[0][skey * 72 + sc * 16 + 8] = kB;
    *(uint4*)&Vt[0][skey * 72 + sc * 16]     = vA;
    *(uint4*)&Vt[0][skey * 72 + sc * 16 + 8] = vB;
    __syncthreads();
    int p = 0;

    for (int kt = 0; kt < ktiles; ++kt) {
        const int kv0 = kt * 64;
        const bool last = (kt + 1 == ktiles);
        if (!last) {   // issue next tile's loads now (latency under compute)
            const int nv0 = kv0 + 64;
            kA = *(const uint4*)&kp[(size_t)(nv0 + skey) * HD + sc * 16];
            kB = *(const uint4*)&kp[(size_t)(nv0 + skey) * HD + sc * 16 + 8];
            vA = *(const uint4*)&vp[(size_t)skey * TT + nv0 + sc * 16];
            vB = *(const uint4*)&vp[(size_t)skey * TT + nv0 + sc * 16 + 8];
        }

        if (kv0 <= q0w + 31) {
            const unsigned short* Kp = Ks[p];
            const unsigned short* Vp = Vt[p];

            // ---- QK^T (swapped): s[f][kb] reg r = S[key=kb*16+4g+r][q=q0f+c]
            f32x4 s[2][4];
            __builtin_amdgcn_s_setprio(1);
#pragma unroll
            for (int kb = 0; kb < 4; ++kb) {
                const bf16x8 k0v = *(const bf16x8*)&Kp[(kb * 16 + c) * 72 + g * 8];
                const bf16x8 k1v = *(const bf16x8*)&Kp[(kb * 16 + c) * 72 + 32 + g * 8];
#pragma unroll
                for (int f = 0; f < 2; ++f) {
                    f32x4 z = {0.f, 0.f, 0.f, 0.f};
                    z = __builtin_amdgcn_mfma_f32_16x16x32_bf16(k0v, qa0[f], z, 0, 0, 0);
                    s[f][kb] = __builtin_amdgcn_mfma_f32_16x16x32_bf16(k1v, qa1[f], z, 0, 0, 0);
                }
            }
            __builtin_amdgcn_s_setprio(0);

            int paw[2][8];
            bool fact[2];
#pragma unroll
            for (int f = 0; f < 2; ++f) {
                const int q0f = q0w + f * 16;
                fact[f] = (kv0 <= q0f + 15);
                if (!fact[f]) continue;   // frag fully masked this tile

                if (kv0 + 63 > q0f) {     // diagonal tile: causal mask
                    const int rhs = q0f + c - kv0;   // key_local > rhs -> mask
#pragma unroll
                    for (int kb = 0; kb < 4; ++kb)
#pragma unroll
                        for (int r = 0; r < 4; ++r)
                            if (kb * 16 + 4 * g + r > rhs) s[f][kb][r] = -INFINITY;
                }

                // row max: in-lane tree + 2 shfl
                float mx;
                {
                    f32x4 t0;
#pragma unroll
                    for (int e = 0; e < 4; ++e)
                        t0[e] = fmaxf(fmaxf(s[f][0][e], s[f][1][e]),
                                      fmaxf(s[f][2][e], s[f][3][e]));
                    mx = fmaxf(fmaxf(t0[0], t0[1]), fmaxf(t0[2], t0[3]));
                }
                mx = fmaxf(mx, __shfl_xor(mx, 16));
                mx = fmaxf(mx, __shfl_xor(mx, 32));

                const bool grow = (__all(mx <= m_r[f]) == 0);
                float alpha = 1.f;
                if (grow) {
                    const float mn = fmaxf(m_r[f], mx);
                    alpha = exp2f(m_r[f] - mn);
                    m_r[f] = mn;
                }

                // p = 2^(s - m); sum in-lane + 2 shfl
                float px[4][4];
#pragma unroll
                for (int kb = 0; kb < 4; ++kb)
#pragma unroll
                    for (int r = 0; r < 4; ++r)
                        px[kb][r] = exp2f(s[f][kb][r] - m_r[f]);
                float psum;
                {
                    f32x4 a0;
#pragma unroll
                    for (int e = 0; e < 4; ++e)
                        a0[e] = (px[0][e] + px[1][e]) + (px[2][e] + px[3][e]);
                    psum = (a0[0] + a0[1]) + (a0[2] + a0[3]);
                }
                psum += __shfl_xor(psum, 16);
                psum += __shfl_xor(psum, 32);
                l_r[f] = (grow ? l_r[f] * alpha : l_r[f]) + psum;

                if (grow) {   // alpha to o-layout (q=4g+r)
                    float alo[4];
#pragma unroll
                    for (int r = 0; r < 4; ++r) alo[r] = __shfl(alpha, 20 * g + r);
#pragma unroll
                    for (int db = 0; db < 4; ++db)
#pragma unroll
                        for (int r = 0; r < 4; ++r) o[f][db][r] *= alo[r];
                }

                // pack + redistribute to PV A-frag layout
                unsigned pk[4][2];
#pragma unroll
                for (int kb = 0; kb < 4; ++kb) {
                    pk[kb][0] = cvt_pk_bf16(px[kb][0], px[kb][1]);
                    pk[kb][1] = cvt_pk_bf16(px[kb][2], px[kb][3]);
                }
                const int sA = c + 32 * (g & 1);
                const int sB = sA + 16;
                const bool hi = (g >= 2);
                unsigned a_, b_;
                a_ = __shfl(pk[0][0], sA); b_ = __shfl(pk[1][0], sA); paw[f][0] = (int)(hi ? b_ : a_);
                a_ = __shfl(pk[0][1], sA); b_ = __shfl(pk[1][1], sA); paw[f][1] = (int)(hi ? b_ : a_);
                a_ = __shfl(pk[0][0], sB); b_ = __shfl(pk[1][0], sB); paw[f][2] = (int)(hi ? b_ : a_);
                a_ = __shfl(pk[0][1], sB); b_ = __shfl(pk[1][1], sB); paw[f][3] = (int)(hi ? b_ : a_);
                a_ = __shfl(pk[2][0], sA); b_ = __shfl(pk[3][0], sA); paw[f][4] = (int)(hi ? b_ : a_);
                a_ = __shfl(pk[2][1], sA); b_ = __shfl(pk[3][1], sA); paw[f][5] = (int)(hi ? b_ : a_);
                a_ = __shfl(pk[2][0], sB); b_ = __shfl(pk[3][0], sB); paw[f][6] = (int)(hi ? b_ : a_);
                a_ = __shfl(pk[2][1], sB); b_ = __shfl(pk[3][1], sB); paw[f][7] = (int)(hi ? b_ : a_);
            }

            // ---- PV: o[f][db] reg r = O[q=q0f+4g+r][d=db*16+c] ----
            __builtin_amdgcn_s_setprio(1);
#pragma unroll
            for (int db = 0; db < 4; ++db) {
                const bf16x8 vb0 = *(const bf16x8*)&Vp[(db * 16 + c) * 72 + g * 8];
                const bf16x8 vb1 = *(const bf16x8*)&Vp[(db * 16 + c) * 72 + 32 + g * 8];
#pragma unroll
                for (int f = 0; f < 2; ++f) {
                    if (!fact[f]) continue;
                    i32x4 w0 = {paw[f][0], paw[f][1], paw[f][2], paw[f][3]};
                    i32x4 w1 = {paw[f][4], paw[f][5], paw[f][6], paw[f][7]};
                    o[f][db] = __builtin_amdgcn_mfma_f32_16x16x32_bf16(
                        __builtin_bit_cast(bf16x8, w0), vb0, o[f][db], 0, 0, 0);
                    o[f][db] = __builtin_amdgcn_mfma_f32_16x16x32_bf16(
                        __builtin_bit_cast(bf16x8, w1), vb1, o[f][db], 0, 0, 0);
                }
            }
            __builtin_amdgcn_s_setprio(0);
        }

        if (!last) {   // write next tile into the other buffer
            const int pn = p ^ 1;
            *(uint4*)&Ks[pn][skey * 72 + sc * 16]     = kA;
            *(uint4*)&Ks[pn][skey * 72 + sc * 16 + 8] = kB;
            *(uint4*)&Vt[pn][skey * 72 + sc * 16]     = vA;
            *(uint4*)&Vt[pn][skey * 72 + sc * 16 + 8] = vB;
        }
        __syncthreads();
        p ^= 1;
    }

    // epilogue: normalize (l at q=c -> shuffle to o-layout q=4g+r)
    unsigned short* op = attn_b + ((size_t)b * TT + q0w) * EE + h * HD;
#pragma unroll
    for (int f = 0; f < 2; ++f) {
        const float lf = l_r[f];
        float linv[4];
#pragma unroll
        for (int r = 0; r < 4; ++r) linv[r] = 1.f / __shfl(lf, 20 * g + r);
#pragma unroll
        for (int db = 0; db < 4; ++db)
#pragma unroll
            for (int r = 0; r < 4; ++r)
                op[(size_t)(f * 16 + 4 * g + r) * EE + db * 16 + c] =
                    f2bf(o[f][db][r] * linv[r]);
    }
}

extern "C" void kernel_launch(void* const* d_in, const int* in_sizes, int n_in,
                              void* d_out, int out_size, void* d_ws, size_t ws_size,
                              hipStream_t stream) {
    const float* x     = (const float*)d_in[0];
    const float* wqkv  = (const float*)d_in[1];
    const float* wproj = (const float*)d_in[2];
    float* out = (float*)d_out;

    unsigned short* ws = (unsigned short*)d_ws;
    unsigned short* q_ws    = ws;                    // [B,H,T,64] (pre-scaled)
    unsigned short* k_ws    = ws + (size_t)BTE;
    unsigned short* v_ws    = ws + 2 * (size_t)BTE;  // [B,H,64,T]
    unsigned short* xb      = ws + 3 * (size_t)BTE;  // [8192][768]
    unsigned short* attn_b  = ws + 4 * (size_t)BTE;  // [8192][768]
    unsigned short* wqkv_t  = ws + 5 * (size_t)BTE;  // [2304][768]
    unsigned short* wproj_t = wqkv_t + (size_t)2304 * 768;

    convx_kernel<<<BTE / 2048, 256, 0, stream>>>(x, xb);
    transw_kernel<<<dim3(2304 / 64, KK / 64), 256, 0, stream>>>(wqkv, wqkv_t, 2304);
    transw_kernel<<<dim3(768 / 64, KK / 64), 256, 0, stream>>>(wproj, wproj_t, 768);

    mfma_gemm_kernel<0><<<dim3(2304 / 128, 8192 / 128), 256, 0, stream>>>(
        xb, wqkv_t, q_ws, k_ws, v_ws, nullptr);
    attn_kernel<<<dim3(TT / 128, HH, BB), 256, 0, stream>>>(q_ws, k_ws, v_ws, attn_b);
    mfma_gemm_kernel<1><<<dim3(EE / 128, 8192 / 128), 256, 0, stream>>>(
        attn_b, wproj_t, nullptr, nullptr, nullptr, out);
}